// Round 11
// baseline (87.978 us; speedup 1.0000x reference)
//
#include <hip/hip_runtime.h>
#include <hip/hip_bf16.h>
#include <math.h>

typedef __bf16 bf16;
typedef __attribute__((ext_vector_type(4))) float f32x4;
typedef __attribute__((ext_vector_type(8))) bf16 bf16x8;

#define M_TOT 16384
#define K_TOT 1024
#define D_EMB 512
#define NT 32          // K tiles of 32

// ============================================================
// Pass 0 (unchanged from r9, verified): W -> fragment-ordered bf16
// image (2 MB). Blob (estrip, kt) = 1 KB:
//   img[((es*32+kt)*64 + lane)*8 + j]
//     = W_cat[es*16 + (lane&15)][kt*32 + (lane>>4)*8 + j]
// ============================================================
__global__ __launch_bounds__(256) void cvt_w_img(
    const float* __restrict__ W_mu, const float* __restrict__ W_logvar,
    bf16* __restrict__ img)
{
    const int c  = blockIdx.x * 256 + threadIdx.x;   // 0..131071
    const int l  = c & 63;
    const int kt = (c >> 6) & 31;
    const int es = c >> 11;                          // 0..63
    const int col = es * 16 + (l & 15);
    const int k0  = kt * 32 + (l >> 4) * 8;
    const float* s = (col < D_EMB) ? (W_mu + (size_t)col * K_TOT + k0)
                                   : (W_logvar + (size_t)(col - D_EMB) * K_TOT + k0);
    f32x4 a = ((const f32x4*)s)[0];
    f32x4 b = ((const f32x4*)s)[1];
    bf16x8 o;
    o[0] = (bf16)a[0]; o[1] = (bf16)a[1]; o[2] = (bf16)a[2]; o[3] = (bf16)a[3];
    o[4] = (bf16)b[0]; o[5] = (bf16)b[1]; o[6] = (bf16)b[2]; o[7] = (bf16)b[3];
    *(bf16x8*)(img + (size_t)c * 8) = o;
}

// ============================================================
// Main GEMM: NO LDS, NO BARRIERS. 256x256 per block, 8 waves as
// 4m x 2n; each wave owns an independent 64x128 output tile.
// Per K-tile (BK=32) per wave:
//   - A: 4 frags f32 direct global->reg (8 dwordx4; wave covers
//     16 rows x 128 B contiguous per frag), cvt in-reg to bf16.
//   - B: 8 frags from fragment-image (1 KB contiguous per frag).
//   - 32 MFMA.
// Pipeline (per wave, register-WAR-safe, compiler-counted vmcnt):
//   iter t: cvt(pfA=A(t)) ; issue loadA(t+1)->pfA ; MFMA(afc,bv=B(t)) ;
//           issue loadB(t+1)->bv
// Duplicate-address waves (A: wc-pairs, B: wr-quads) are co-resident
// on the CU -> L1 serves the duplicates. No inter-wave sync at all;
// waves drift and self-overlap (load phase of one hides MFMA of other).
// ============================================================
__global__ __launch_bounds__(512, 2) void gpe_gemm(
    const float* __restrict__ x,
    const bf16* __restrict__ wimg,
    const float* __restrict__ b_mu,
    const float* __restrict__ b_logvar,
    float* __restrict__ out)         // [2][16384][512]
{
    const int tid  = threadIdx.x;
    const int lane = tid & 63;
    const int wid  = tid >> 6;        // 0..7
    const int wr   = wid >> 1;        // 0..3  (64-row band)
    const int wc   = wid & 1;         // 0..1  (128-col band)

    // T1: bijective XCD swizzle (grid 256 = 8 XCD x 32); bn inner so the
    // 4 blocks sharing an x-panel sit on one XCD's L2.
    const int bid = blockIdx.x;
    const int swz = (bid & 7) * 32 + (bid >> 3);
    const int bn  = swz & 3;          // 0..3 (E quadrant, 256 cols)
    const int bm  = swz >> 2;         // 0..63

    const int fr  = lane & 15;
    const int g16 = lane >> 4;        // k-chunk 0..3

    // A: frag m covers rows bm*256 + wr*64 + m*16 + fr, k-chunk g16*8 (+0/4)
    const float* __restrict__ Abase =
        x + (size_t)(bm * 256 + wr * 64 + fr) * K_TOT + g16 * 8;

    // B image: wave needs estrips bn*16 + wc*8 + n, n=0..7
    const bf16* __restrict__ bb =
        wimg + (size_t)(bn * 16 + wc * 8) * 16384 + lane * 8;

    f32x4 acc[4][8];
#pragma unroll
    for (int m = 0; m < 4; ++m)
#pragma unroll
        for (int n = 0; n < 8; ++n)
            acc[m][n] = (f32x4){0.f, 0.f, 0.f, 0.f};

    f32x4  pfA[8];    // next-tile A f32 (2 f32x4 per frag)
    bf16x8 afc[4];    // current-tile A bf16 frags
    bf16x8 bv[8];     // current-tile B frags

    auto loadA = [&](int t) {
#pragma unroll
        for (int m = 0; m < 4; ++m) {
            const float* p = Abase + (size_t)m * 16 * K_TOT + t * 32;
            pfA[2 * m]     = *(const f32x4*)p;
            pfA[2 * m + 1] = *(const f32x4*)(p + 4);
        }
    };
    auto loadB = [&](int t) {
#pragma unroll
        for (int n = 0; n < 8; ++n)
            bv[n] = *(const bf16x8*)(bb + (size_t)n * 16384 + t * 512);
    };
    auto cvtA = [&]() {
#pragma unroll
        for (int m = 0; m < 4; ++m) {
            bf16x8 w;
#pragma unroll
            for (int j = 0; j < 4; ++j) {
                w[j]     = (bf16)pfA[2 * m][j];
                w[j + 4] = (bf16)pfA[2 * m + 1][j];
            }
            afc[m] = w;
        }
    };

    // prologue: issue tile-0 loads (A first, then B)
    loadA(0);
    loadB(0);

    for (int t = 0; t < NT; ++t) {
        cvtA();                        // compiler waits A(t) here (counted)
        if (t + 1 < NT) loadA(t + 1);  // WAR on pfA: after cvt read
        __builtin_amdgcn_s_setprio(1);
#pragma unroll
        for (int n = 0; n < 8; ++n)    // compiler waits B(t) before first use
#pragma unroll
            for (int m = 0; m < 4; ++m)
                acc[m][n] = __builtin_amdgcn_mfma_f32_16x16x32_bf16(
                    afc[m], bv[n], acc[m][n], 0, 0, 0);
        __builtin_amdgcn_s_setprio(0);
        if (t + 1 < NT) loadB(t + 1);  // WAR on bv: after MFMA reads
    }

    // ---- epilogue: bias (+ exp for logvar head) ----
    const bool is_mu = (bn < 2);
    const float* __restrict__ bias = is_mu ? b_mu : b_logvar;
    const int cb = (bn & 1) * 256;
    float* __restrict__ obase = is_mu ? out : (out + (size_t)M_TOT * D_EMB);

#pragma unroll
    for (int m = 0; m < 4; ++m) {
        const int row0 = bm * 256 + wr * 64 + m * 16 + g16 * 4;
#pragma unroll
        for (int n = 0; n < 8; ++n) {
            const int c = cb + wc * 128 + n * 16 + fr;
            const float bvs = bias[c];
#pragma unroll
            for (int j = 0; j < 4; ++j) {
                float v = acc[m][n][j] + bvs;
                if (!is_mu) v = __expf(0.5f * v);
                obase[(size_t)(row0 + j) * D_EMB + c] = v;
            }
        }
    }
}

// ============================================================
// Fallback (no workspace): round-1 f32-staging GEMM
// ============================================================
#define LDS_STRIDE 40
__global__ __launch_bounds__(256) void gpe_gemm_fb(
    const float* __restrict__ x, const float* __restrict__ W_mu,
    const float* __restrict__ b_mu, const float* __restrict__ W_logvar,
    const float* __restrict__ b_logvar, float* __restrict__ out)
{
    __shared__ __align__(16) bf16 As[128][LDS_STRIDE];
    __shared__ __align__(16) bf16 Bs[128][LDS_STRIDE];
    typedef __attribute__((ext_vector_type(4))) bf16 bf16x4;
    const int tid = threadIdx.x, lane = tid & 63, wid = tid >> 6;
    const int wr = wid >> 1, wc = wid & 1;
    const int bn = blockIdx.x & 7, bm = blockIdx.x >> 3;
    const int ebase = bn * 128;
    const bool is_mu = (ebase < D_EMB);
    const float* Wp = is_mu ? (W_mu + (size_t)ebase * K_TOT)
                            : (W_logvar + (size_t)(ebase - D_EMB) * K_TOT);
    const float* bias = is_mu ? b_mu : b_logvar;
    const int cbase = is_mu ? ebase : (ebase - D_EMB);
    float* obase = is_mu ? out : (out + (size_t)M_TOT * D_EMB);
    const float* Ap = x + (size_t)(bm * 128) * K_TOT;
    f32x4 acc[4][4];
#pragma unroll
    for (int m = 0; m < 4; ++m)
#pragma unroll
        for (int n = 0; n < 4; ++n) acc[m][n] = (f32x4){0.f, 0.f, 0.f, 0.f};
    const int fr = lane & 15, fk = (lane >> 4) * 8;
    const int arow = wr * 64 + fr, brow = wc * 64 + fr;
    for (int kt = 0; kt < K_TOT / 32; ++kt) {
        const int k0 = kt * 32;
#pragma unroll
        for (int s = 0; s < 4; ++s) {
            const int idx = s * 256 + tid;
            const int row = idx >> 3, col = (idx & 7) << 2;
            f32x4 va = *reinterpret_cast<const f32x4*>(Ap + (size_t)row * K_TOT + k0 + col);
            f32x4 vb = *reinterpret_cast<const f32x4*>(Wp + (size_t)row * K_TOT + k0 + col);
            bf16x4 ha, hb;
#pragma unroll
            for (int j = 0; j < 4; ++j) { ha[j] = (bf16)va[j]; hb[j] = (bf16)vb[j]; }
            *reinterpret_cast<bf16x4*>(&As[row][col]) = ha;
            *reinterpret_cast<bf16x4*>(&Bs[row][col]) = hb;
        }
        __syncthreads();
        bf16x8 af[4], bfv[4];
#pragma unroll
        for (int m = 0; m < 4; ++m)
            af[m] = *reinterpret_cast<const bf16x8*>(&As[arow + m * 16][fk]);
#pragma unroll
        for (int n = 0; n < 4; ++n)
            bfv[n] = *reinterpret_cast<const bf16x8*>(&Bs[brow + n * 16][fk]);
#pragma unroll
        for (int m = 0; m < 4; ++m)
#pragma unroll
            for (int n = 0; n < 4; ++n)
                acc[m][n] = __builtin_amdgcn_mfma_f32_16x16x32_bf16(af[m], bfv[n], acc[m][n], 0, 0, 0);
        __syncthreads();
    }
#pragma unroll
    for (int m = 0; m < 4; ++m) {
        const int rbase = bm * 128 + wr * 64 + m * 16 + (lane >> 4) * 4;
#pragma unroll
        for (int n = 0; n < 4; ++n) {
            const int c = cbase + wc * 64 + n * 16 + (lane & 15);
            const float bv = bias[c];
#pragma unroll
            for (int j = 0; j < 4; ++j) {
                float v = acc[m][n][j] + bv;
                if (!is_mu) v = __expf(0.5f * v);
                obase[(size_t)(rbase + j) * D_EMB + c] = v;
            }
        }
    }
}

extern "C" void kernel_launch(void* const* d_in, const int* in_sizes, int n_in,
                              void* d_out, int out_size, void* d_ws, size_t ws_size,
                              hipStream_t stream) {
    const float* x        = (const float*)d_in[0];
    const float* W_mu     = (const float*)d_in[1];
    const float* b_mu     = (const float*)d_in[2];
    const float* W_logvar = (const float*)d_in[3];
    const float* b_logvar = (const float*)d_in[4];
    float* out = (float*)d_out;

    const size_t ws_needed = (size_t)1024 * 1024 * sizeof(bf16);   // 2 MB W image

    if (ws_size >= ws_needed) {
        bf16* wimg = (bf16*)d_ws;
        cvt_w_img<<<512, 256, 0, stream>>>(W_mu, W_logvar, wimg);
        gpe_gemm<<<256, 512, 0, stream>>>(x, wimg, b_mu, b_logvar, out);
    } else {
        gpe_gemm_fb<<<1024, 256, 0, stream>>>(x, W_mu, b_mu, W_logvar, b_logvar, out);
    }
}

// Round 12
// 54.862 us; speedup vs baseline: 1.6036x; 1.6036x over previous
//
#include <hip/hip_runtime.h>
#include <hip/hip_bf16.h>
#include <math.h>

typedef __bf16 bf16;
typedef __attribute__((ext_vector_type(4))) float f32x4;
typedef __attribute__((ext_vector_type(4))) bf16 bf16x4;
typedef __attribute__((ext_vector_type(8))) bf16 bf16x8;

#define M_TOT 16384
#define K_TOT 1024
#define D_EMB 512
#define NT 32          // K tiles of 32

// ============================================================
// Pass 0 (unchanged from r9, verified): W -> fragment-ordered bf16
// image (2 MB). Blob (es, kt) = 1 KB:
//   img[((es*32+kt)*64 + l)*8 + j]
//     = W_cat[es*16 + (l&15)][kt*32 + (l>>4)*8 + j]
// ============================================================
__global__ __launch_bounds__(256) void cvt_w_img(
    const float* __restrict__ W_mu, const float* __restrict__ W_logvar,
    bf16* __restrict__ img)
{
    const int c  = blockIdx.x * 256 + threadIdx.x;   // 0..131071
    const int l  = c & 63;
    const int kt = (c >> 6) & 31;
    const int es = c >> 11;                          // 0..63
    const int col = es * 16 + (l & 15);
    const int k0  = kt * 32 + (l >> 4) * 8;
    const float* s = (col < D_EMB) ? (W_mu + (size_t)col * K_TOT + k0)
                                   : (W_logvar + (size_t)(col - D_EMB) * K_TOT + k0);
    f32x4 a = ((const f32x4*)s)[0];
    f32x4 b = ((const f32x4*)s)[1];
    bf16x8 o;
    o[0] = (bf16)a[0]; o[1] = (bf16)a[1]; o[2] = (bf16)a[2]; o[3] = (bf16)a[3];
    o[4] = (bf16)b[0]; o[5] = (bf16)b[1]; o[6] = (bf16)b[2]; o[7] = (bf16)b[3];
    *(bf16x8*)(img + (size_t)c * 8) = o;
}

// ============================================================
// Tall-skinny GEMM: block = 64 rows x ALL 1024 cols, grid 256
// (one block per 64-row slice -> x read EXACTLY ONCE, no dup,
// no separate convert pass, no ws for x). 8 waves = 1x8; wave
// tile 64x128 (acc[4][8]). BK=32, 32 K-tiles.
//   A: 8KB f32/tile -> regs -> cvt -> LDS (linear 64B rows, bank-
//      uniform reads/writes, no swizzle), double-buffered 8KB total.
//   B: global->VGPR from fragment image (L2-resident 2MB), tile-
//      level ping-pong bvA/bvB issued one full tile ahead.
// Sync: one raw s_barrier + lgkmcnt(0) per tile, placed AFTER the
// MFMA cluster. No vmcnt(0) anywhere in the loop (B/A in-flight
// loads cross barriers; compiler emits counted waits off reg deps).
// Ledger: afc reads (buf P) retire before this tile's lgkm(0)+bar;
// next tile writes P after that bar -> WAR safe. cwA writes (P^1)
// drain at this bar -> visible to reads at t+1. bv/pfA are register
// ping-pongs with >= 1 tile of slack.
// ============================================================
__global__ __launch_bounds__(512, 1) void gpe_tall(
    const float* __restrict__ x,
    const bf16* __restrict__ wimg,
    const float* __restrict__ b_mu,
    const float* __restrict__ b_logvar,
    float* __restrict__ out)         // [2][16384][512]
{
    __shared__ __align__(16) bf16 Alds[2][64 * 32];   // 8 KB

    const int tid  = threadIdx.x;
    const int lane = tid & 63;
    const int wc   = tid >> 6;        // 0..7 : 128-col band
    const int fr   = lane & 15;
    const int g16  = lane >> 4;
    const int bm   = blockIdx.x;      // 0..255 : 64-row slice

    // ---- A staging: thread owns 4 f32 of one row ----
    const int arow = tid >> 3;                        // 0..63
    const int aslot = tid & 7;                        // 8 slots of 4 f32
    const float* __restrict__ Asrc = x + (size_t)(bm * 64 + arow) * K_TOT + aslot * 4;
    const int awoff = arow * 32 + aslot * 4;          // elems, linear

    // ---- B image base: estrips wc*8 + ns, ns = 0..7 ----
    const bf16* __restrict__ bb = wimg + (size_t)(wc * 8) * (NT * 512) + lane * 8;
    // bv(ns) at tile t: bb + ns*(NT*512) + t*512

    f32x4 acc[4][8];
#pragma unroll
    for (int m = 0; m < 4; ++m)
#pragma unroll
        for (int n = 0; n < 8; ++n)
            acc[m][n] = (f32x4){0.f, 0.f, 0.f, 0.f};

    f32x4  pfA;        // next-tile A f32 (4 elems)
    bf16x8 bvA[8], bvB[8];

    auto gloadA = [&](int t) { pfA = *(const f32x4*)(Asrc + t * 32); };
    auto cwA = [&](bf16* base) {
        bf16x4 w;
#pragma unroll
        for (int j = 0; j < 4; ++j) w[j] = (bf16)pfA[j];
        *(bf16x4*)&base[awoff] = w;                   // ds_write_b64
    };
    auto loadB = [&](int t, bf16x8 (&bv)[8]) {
#pragma unroll
        for (int ns = 0; ns < 8; ++ns)
            bv[ns] = *(const bf16x8*)(bb + (size_t)ns * (NT * 512) + t * 512);
    };

    // ---- prologue ----
    gloadA(0);
    cwA(&Alds[0][0]);                 // compiler waits A(0)
    gloadA(1);
    loadB(0, bvA);
    asm volatile("s_waitcnt lgkmcnt(0)" ::: "memory");
    __builtin_amdgcn_s_barrier();

#define TILE_BODY(T, P, BVC, BVN)                                              \
    {                                                                          \
        const int t = (T);                                                     \
        if (t + 1 < NT) loadB(t + 1, BVN);       /* full-tile slack */         \
        bf16x8 afc[4];                                                         \
        _Pragma("unroll")                                                      \
        for (int m = 0; m < 4; ++m)                                            \
            afc[m] = *(const bf16x8*)&Alds[P][(m * 16 + fr) * 32 + g16 * 8];   \
        if (t + 1 < NT) {                                                      \
            cwA(&Alds[(P) ^ 1][0]);              /* A(t+1) -> other buf */     \
            if (t + 2 < NT) gloadA(t + 2);                                     \
        }                                                                      \
        __builtin_amdgcn_s_setprio(1);                                         \
        _Pragma("unroll")                                                      \
        for (int ns = 0; ns < 8; ++ns)                                         \
            _Pragma("unroll")                                                  \
            for (int m = 0; m < 4; ++m)                                        \
                acc[m][ns] = __builtin_amdgcn_mfma_f32_16x16x32_bf16(          \
                    afc[m], BVC[ns], acc[m][ns], 0, 0, 0);                     \
        __builtin_amdgcn_s_setprio(0);                                         \
        asm volatile("s_waitcnt lgkmcnt(0)" ::: "memory");                     \
        __builtin_amdgcn_s_barrier();                                          \
    }

    for (int t0 = 0; t0 < NT; t0 += 2) {
        TILE_BODY(t0,     0, bvA, bvB)
        TILE_BODY(t0 + 1, 1, bvB, bvA)
    }
#undef TILE_BODY

    // ---- epilogue: bias (+ exp for logvar head) ----
    const bool is_mu = (wc < 4);
    const float* __restrict__ bias = is_mu ? b_mu : b_logvar;
    float* __restrict__ obase = is_mu ? out : (out + (size_t)M_TOT * D_EMB);
    const int clbase = (wc & 3) * 128;

#pragma unroll
    for (int m = 0; m < 4; ++m) {
        const int row0 = bm * 64 + m * 16 + g16 * 4;
#pragma unroll
        for (int ns = 0; ns < 8; ++ns) {
            const int cl = clbase + ns * 16 + fr;
            const float bvs = bias[cl];
#pragma unroll
            for (int j = 0; j < 4; ++j) {
                float v = acc[m][ns][j] + bvs;
                if (!is_mu) v = __expf(0.5f * v);
                obase[(size_t)(row0 + j) * D_EMB + cl] = v;
            }
        }
    }
}

// ============================================================
// Fallback (no workspace): round-1 f32-staging GEMM
// ============================================================
#define LDS_STRIDE 40
__global__ __launch_bounds__(256) void gpe_gemm_fb(
    const float* __restrict__ x, const float* __restrict__ W_mu,
    const float* __restrict__ b_mu, const float* __restrict__ W_logvar,
    const float* __restrict__ b_logvar, float* __restrict__ out)
{
    __shared__ __align__(16) bf16 As[128][LDS_STRIDE];
    __shared__ __align__(16) bf16 Bs[128][LDS_STRIDE];
    const int tid = threadIdx.x, lane = tid & 63, wid = tid >> 6;
    const int wr = wid >> 1, wcn = wid & 1;
    const int bn = blockIdx.x & 7, bm = blockIdx.x >> 3;
    const int ebase = bn * 128;
    const bool is_mu = (ebase < D_EMB);
    const float* Wp = is_mu ? (W_mu + (size_t)ebase * K_TOT)
                            : (W_logvar + (size_t)(ebase - D_EMB) * K_TOT);
    const float* bias = is_mu ? b_mu : b_logvar;
    const int cbase = is_mu ? ebase : (ebase - D_EMB);
    float* obase = is_mu ? out : (out + (size_t)M_TOT * D_EMB);
    const float* Ap = x + (size_t)(bm * 128) * K_TOT;
    f32x4 acc[4][4];
#pragma unroll
    for (int m = 0; m < 4; ++m)
#pragma unroll
        for (int n = 0; n < 4; ++n) acc[m][n] = (f32x4){0.f, 0.f, 0.f, 0.f};
    const int fr = lane & 15, fk = (lane >> 4) * 8;
    const int arow = wr * 64 + fr, brow = wcn * 64 + fr;
    for (int kt = 0; kt < K_TOT / 32; ++kt) {
        const int k0 = kt * 32;
#pragma unroll
        for (int s = 0; s < 4; ++s) {
            const int idx = s * 256 + tid;
            const int row = idx >> 3, col = (idx & 7) << 2;
            f32x4 va = *reinterpret_cast<const f32x4*>(Ap + (size_t)row * K_TOT + k0 + col);
            f32x4 vb = *reinterpret_cast<const f32x4*>(Wp + (size_t)row * K_TOT + k0 + col);
            bf16x4 ha, hb;
#pragma unroll
            for (int j = 0; j < 4; ++j) { ha[j] = (bf16)va[j]; hb[j] = (bf16)vb[j]; }
            *reinterpret_cast<bf16x4*>(&As[row][col]) = ha;
            *reinterpret_cast<bf16x4*>(&Bs[row][col]) = hb;
        }
        __syncthreads();
        bf16x8 af[4], bfv[4];
#pragma unroll
        for (int m = 0; m < 4; ++m)
            af[m] = *reinterpret_cast<const bf16x8*>(&As[arow + m * 16][fk]);
#pragma unroll
        for (int n = 0; n < 4; ++n)
            bfv[n] = *reinterpret_cast<const bf16x8*>(&Bs[brow + n * 16][fk]);
#pragma unroll
        for (int m = 0; m < 4; ++m)
#pragma unroll
            for (int n = 0; n < 4; ++n)
                acc[m][n] = __builtin_amdgcn_mfma_f32_16x16x32_bf16(af[m], bfv[n], acc[m][n], 0, 0, 0);
        __syncthreads();
    }
#pragma unroll
    for (int m = 0; m < 4; ++m) {
        const int rbase = bm * 128 + wr * 64 + m * 16 + (lane >> 4) * 4;
#pragma unroll
        for (int n = 0; n < 4; ++n) {
            const int c = cbase + wcn * 64 + n * 16 + (lane & 15);
            const float bv = bias[c];
#pragma unroll
            for (int j = 0; j < 4; ++j) {
                float v = acc[m][n][j] + bv;
                if (!is_mu) v = __expf(0.5f * v);
                obase[(size_t)(rbase + j) * D_EMB + c] = v;
            }
        }
    }
}

extern "C" void kernel_launch(void* const* d_in, const int* in_sizes, int n_in,
                              void* d_out, int out_size, void* d_ws, size_t ws_size,
                              hipStream_t stream) {
    const float* x        = (const float*)d_in[0];
    const float* W_mu     = (const float*)d_in[1];
    const float* b_mu     = (const float*)d_in[2];
    const float* W_logvar = (const float*)d_in[3];
    const float* b_logvar = (const float*)d_in[4];
    float* out = (float*)d_out;

    const size_t ws_needed = (size_t)1024 * 1024 * sizeof(bf16);   // 2 MB W image

    if (ws_size >= ws_needed) {
        bf16* wimg = (bf16*)d_ws;
        cvt_w_img<<<512, 256, 0, stream>>>(W_mu, W_logvar, wimg);
        gpe_tall<<<256, 512, 0, stream>>>(x, wimg, b_mu, b_logvar, out);
    } else {
        gpe_gemm_fb<<<1024, 256, 0, stream>>>(x, W_mu, b_mu, W_logvar, b_logvar, out);
    }
}

// Round 13
// 53.720 us; speedup vs baseline: 1.6377x; 1.0213x over previous
//
#include <hip/hip_runtime.h>
#include <hip/hip_bf16.h>
#include <math.h>

typedef __bf16 bf16;
typedef __attribute__((ext_vector_type(4))) float f32x4;
typedef __attribute__((ext_vector_type(4))) bf16 bf16x4;
typedef __attribute__((ext_vector_type(8))) bf16 bf16x8;

#define M_TOT 16384
#define K_TOT 1024
#define D_EMB 512
#define NT 32          // K tiles of 32

// ============================================================
// Pass 0 (unchanged, verified r9-r12): W -> fragment-ordered bf16
// image (2 MB). Blob (es, kt) = 1 KB:
//   img[((es*32+kt)*64 + l)*8 + j]
//     = W_cat[es*16 + (l&15)][kt*32 + (l>>4)*8 + j]
// ============================================================
__global__ __launch_bounds__(256) void cvt_w_img(
    const float* __restrict__ W_mu, const float* __restrict__ W_logvar,
    bf16* __restrict__ img)
{
    const int c  = blockIdx.x * 256 + threadIdx.x;   // 0..131071
    const int l  = c & 63;
    const int kt = (c >> 6) & 31;
    const int es = c >> 11;                          // 0..63
    const int col = es * 16 + (l & 15);
    const int k0  = kt * 32 + (l >> 4) * 8;
    const float* s = (col < D_EMB) ? (W_mu + (size_t)col * K_TOT + k0)
                                   : (W_logvar + (size_t)(col - D_EMB) * K_TOT + k0);
    f32x4 a = ((const f32x4*)s)[0];
    f32x4 b = ((const f32x4*)s)[1];
    bf16x8 o;
    o[0] = (bf16)a[0]; o[1] = (bf16)a[1]; o[2] = (bf16)a[2]; o[3] = (bf16)a[3];
    o[4] = (bf16)b[0]; o[5] = (bf16)b[1]; o[6] = (bf16)b[2]; o[7] = (bf16)b[3];
    *(bf16x8*)(img + (size_t)c * 8) = o;
}

// ============================================================
// Tall-skinny, WHOLE-K-IN-LDS GEMM. Block = 64 rows x all 1024 cols,
// grid 256 (x read exactly once). 8 waves = 1x8; wave = 64x128.
//   Staging (once): 64x1024 f32 -> reg -> cvt -> swizzled ds_write,
//     Alds[64][128 slots of 8 bf16] = 128 KB. Slot s stored at
//     s ^ (row&7). Thread map slot-strided (slot = (tid&7) + 8j) ->
//     writes 2 lanes/bank (free). ONE __syncthreads() total.
//   K-loop (barrier-free): per tile 4 swizzled ds_read_b128
//     (2 lanes/bank, free) + 32 MFMA + B-prefetch issue.
//   B: global->VGPR from fragment image, 2-tile-deep ping-pong
//     (bvA/bvB), ~2 wave-tiles of latency slack.
// Waves fully independent after the single barrier -> LDS/MFMA/L2
// phases of different waves overlap by drift; epilogue staggers.
// ============================================================
__global__ __launch_bounds__(512, 1) void gpe_tall2(
    const float* __restrict__ x,
    const bf16* __restrict__ wimg,
    const float* __restrict__ b_mu,
    const float* __restrict__ b_logvar,
    float* __restrict__ out)         // [2][16384][512]
{
    __shared__ __align__(16) bf16 Alds[64 * 1024];   // 128 KB

    const int tid  = threadIdx.x;
    const int lane = tid & 63;
    const int wc   = tid >> 6;        // 0..7 : 128-col band
    const int fr   = lane & 15;
    const int g16  = lane >> 4;       // 0..3
    const int frx  = fr & 7;          // read-swizzle XOR
    const int bm   = blockIdx.x;      // 0..255 : 64-row slice

    // ---- B image: estrips wc*8 + ns ----
    const bf16* __restrict__ bb = wimg + (size_t)(wc * 8) * (NT * 512) + lane * 8;

    bf16x8 bvA[8], bvB[8];
    auto loadB = [&](int t, bf16x8 (&bv)[8]) {
#pragma unroll
        for (int ns = 0; ns < 8; ++ns)
            bv[ns] = *(const bf16x8*)(bb + (size_t)ns * (NT * 512) + t * 512);
    };

    // issue first two B tiles; the staging barrier's drain makes them ready
    loadB(0, bvA);
    loadB(1, bvB);

    // ---- stage entire 64x1024 A slice (f32 -> bf16, swizzled) ----
    {
        const int arow = tid >> 3;                    // 0..63
        const int sl0  = tid & 7;
        const float* __restrict__ Asrc = x + (size_t)(bm * 64 + arow) * K_TOT;
        const int rx = arow & 7;
#pragma unroll
        for (int j = 0; j < 16; ++j) {
            const int slot = sl0 + 8 * j;             // slot&7 = sl0 (write-balanced)
            f32x4 a = *(const f32x4*)(Asrc + slot * 8);
            f32x4 b = *(const f32x4*)(Asrc + slot * 8 + 4);
            bf16x8 w;
#pragma unroll
            for (int q = 0; q < 4; ++q) { w[q] = (bf16)a[q]; w[q + 4] = (bf16)b[q]; }
            *(bf16x8*)&Alds[arow * 1024 + (slot ^ rx) * 8] = w;
        }
    }
    __syncthreads();   // the ONLY barrier

    f32x4 acc[4][8];
#pragma unroll
    for (int m = 0; m < 4; ++m)
#pragma unroll
        for (int n = 0; n < 8; ++n)
            acc[m][n] = (f32x4){0.f, 0.f, 0.f, 0.f};

#define TILE_BODY(T, BVC)                                                      \
    {                                                                          \
        const int t = (T);                                                     \
        bf16x8 afc[4];                                                         \
        _Pragma("unroll")                                                      \
        for (int m = 0; m < 4; ++m)                                            \
            afc[m] = *(const bf16x8*)&Alds[(m * 16 + fr) * 1024                \
                                           + ((t * 4 + g16) ^ frx) * 8];       \
        __builtin_amdgcn_s_setprio(1);                                         \
        _Pragma("unroll")                                                      \
        for (int ns = 0; ns < 8; ++ns)                                         \
            _Pragma("unroll")                                                  \
            for (int m = 0; m < 4; ++m)                                        \
                acc[m][ns] = __builtin_amdgcn_mfma_f32_16x16x32_bf16(          \
                    afc[m], BVC[ns], acc[m][ns], 0, 0, 0);                     \
        __builtin_amdgcn_s_setprio(0);                                         \
        if (t + 2 < NT) loadB(t + 2, BVC);   /* reuse buffer just consumed */  \
    }

    for (int t0 = 0; t0 < NT; t0 += 2) {
        TILE_BODY(t0,     bvA)
        TILE_BODY(t0 + 1, bvB)
    }
#undef TILE_BODY

    // ---- epilogue: bias (+ exp for logvar head); no barrier before,
    //      waves store independently (staggered by drift) ----
    const bool is_mu = (wc < 4);
    const float* __restrict__ bias = is_mu ? b_mu : b_logvar;
    float* __restrict__ obase = is_mu ? out : (out + (size_t)M_TOT * D_EMB);
    const int clbase = (wc & 3) * 128;

#pragma unroll
    for (int m = 0; m < 4; ++m) {
        const int row0 = bm * 64 + m * 16 + g16 * 4;
#pragma unroll
        for (int ns = 0; ns < 8; ++ns) {
            const int cl = clbase + ns * 16 + fr;
            const float bvs = bias[cl];
#pragma unroll
            for (int j = 0; j < 4; ++j) {
                float v = acc[m][ns][j] + bvs;
                if (!is_mu) v = __expf(0.5f * v);
                obase[(size_t)(row0 + j) * D_EMB + cl] = v;
            }
        }
    }
}

// ============================================================
// Fallback (no workspace): round-1 f32-staging GEMM
// ============================================================
#define LDS_STRIDE 40
__global__ __launch_bounds__(256) void gpe_gemm_fb(
    const float* __restrict__ x, const float* __restrict__ W_mu,
    const float* __restrict__ b_mu, const float* __restrict__ W_logvar,
    const float* __restrict__ b_logvar, float* __restrict__ out)
{
    __shared__ __align__(16) bf16 As[128][LDS_STRIDE];
    __shared__ __align__(16) bf16 Bs[128][LDS_STRIDE];
    const int tid = threadIdx.x, lane = tid & 63, wid = tid >> 6;
    const int wr = wid >> 1, wcn = wid & 1;
    const int bn = blockIdx.x & 7, bm = blockIdx.x >> 3;
    const int ebase = bn * 128;
    const bool is_mu = (ebase < D_EMB);
    const float* Wp = is_mu ? (W_mu + (size_t)ebase * K_TOT)
                            : (W_logvar + (size_t)(ebase - D_EMB) * K_TOT);
    const float* bias = is_mu ? b_mu : b_logvar;
    const int cbase = is_mu ? ebase : (ebase - D_EMB);
    float* obase = is_mu ? out : (out + (size_t)M_TOT * D_EMB);
    const float* Ap = x + (size_t)(bm * 128) * K_TOT;
    f32x4 acc[4][4];
#pragma unroll
    for (int m = 0; m < 4; ++m)
#pragma unroll
        for (int n = 0; n < 4; ++n) acc[m][n] = (f32x4){0.f, 0.f, 0.f, 0.f};
    const int fr = lane & 15, fk = (lane >> 4) * 8;
    const int arow = wr * 64 + fr, brow = wcn * 64 + fr;
    for (int kt = 0; kt < K_TOT / 32; ++kt) {
        const int k0 = kt * 32;
#pragma unroll
        for (int s = 0; s < 4; ++s) {
            const int idx = s * 256 + tid;
            const int row = idx >> 3, col = (idx & 7) << 2;
            f32x4 va = *reinterpret_cast<const f32x4*>(Ap + (size_t)row * K_TOT + k0 + col);
            f32x4 vb = *reinterpret_cast<const f32x4*>(Wp + (size_t)row * K_TOT + k0 + col);
            bf16x4 ha, hb;
#pragma unroll
            for (int j = 0; j < 4; ++j) { ha[j] = (bf16)va[j]; hb[j] = (bf16)vb[j]; }
            *reinterpret_cast<bf16x4*>(&As[row][col]) = ha;
            *reinterpret_cast<bf16x4*>(&Bs[row][col]) = hb;
        }
        __syncthreads();
        bf16x8 af[4], bfv[4];
#pragma unroll
        for (int m = 0; m < 4; ++m)
            af[m] = *reinterpret_cast<const bf16x8*>(&As[arow + m * 16][fk]);
#pragma unroll
        for (int n = 0; n < 4; ++n)
            bfv[n] = *reinterpret_cast<const bf16x8*>(&Bs[brow + n * 16][fk]);
#pragma unroll
        for (int m = 0; m < 4; ++m)
#pragma unroll
            for (int n = 0; n < 4; ++n)
                acc[m][n] = __builtin_amdgcn_mfma_f32_16x16x32_bf16(af[m], bfv[n], acc[m][n], 0, 0, 0);
        __syncthreads();
    }
#pragma unroll
    for (int m = 0; m < 4; ++m) {
        const int rbase = bm * 128 + wr * 64 + m * 16 + (lane >> 4) * 4;
#pragma unroll
        for (int n = 0; n < 4; ++n) {
            const int c = cbase + wcn * 64 + n * 16 + (lane & 15);
            const float bv = bias[c];
#pragma unroll
            for (int j = 0; j < 4; ++j) {
                float v = acc[m][n][j] + bv;
                if (!is_mu) v = __expf(0.5f * v);
                obase[(size_t)(rbase + j) * D_EMB + c] = v;
            }
        }
    }
}

extern "C" void kernel_launch(void* const* d_in, const int* in_sizes, int n_in,
                              void* d_out, int out_size, void* d_ws, size_t ws_size,
                              hipStream_t stream) {
    const float* x        = (const float*)d_in[0];
    const float* W_mu     = (const float*)d_in[1];
    const float* b_mu     = (const float*)d_in[2];
    const float* W_logvar = (const float*)d_in[3];
    const float* b_logvar = (const float*)d_in[4];
    float* out = (float*)d_out;

    const size_t ws_needed = (size_t)1024 * 1024 * sizeof(bf16);   // 2 MB W image

    if (ws_size >= ws_needed) {
        bf16* wimg = (bf16*)d_ws;
        cvt_w_img<<<512, 256, 0, stream>>>(W_mu, W_logvar, wimg);
        gpe_tall2<<<256, 512, 0, stream>>>(x, wimg, b_mu, b_logvar, out);
    } else {
        gpe_gemm_fb<<<1024, 256, 0, stream>>>(x, W_mu, b_mu, W_logvar, b_logvar, out);
    }
}

// Round 14
// 48.567 us; speedup vs baseline: 1.8115x; 1.1061x over previous
//
#include <hip/hip_runtime.h>
#include <hip/hip_bf16.h>
#include <math.h>

typedef __bf16 bf16;
typedef __attribute__((ext_vector_type(4))) float f32x4;
typedef __attribute__((ext_vector_type(4))) bf16 bf16x4;
typedef __attribute__((ext_vector_type(8))) bf16 bf16x8;

#define M_TOT 16384
#define K_TOT 1024
#define D_EMB 512
#define NT 32          // K tiles of 32

// ============================================================
// Pass 0 (unchanged, verified r9-r13): W -> fragment-ordered bf16
// image (2 MB). Blob (es, kt) = 1 KB:
//   img[es*16384 + kt*512 + l*8 + j]
//     = W_cat[es*16 + (l&15)][kt*32 + (l>>4)*8 + j]
// ============================================================
__global__ __launch_bounds__(256) void cvt_w_img(
    const float* __restrict__ W_mu, const float* __restrict__ W_logvar,
    bf16* __restrict__ img)
{
    const int c  = blockIdx.x * 256 + threadIdx.x;   // 0..131071
    const int l  = c & 63;
    const int kt = (c >> 6) & 31;
    const int es = c >> 11;                          // 0..63
    const int col = es * 16 + (l & 15);
    const int k0  = kt * 32 + (l >> 4) * 8;
    const float* s = (col < D_EMB) ? (W_mu + (size_t)col * K_TOT + k0)
                                   : (W_logvar + (size_t)(col - D_EMB) * K_TOT + k0);
    f32x4 a = ((const f32x4*)s)[0];
    f32x4 b = ((const f32x4*)s)[1];
    bf16x8 o;
    o[0] = (bf16)a[0]; o[1] = (bf16)a[1]; o[2] = (bf16)a[2]; o[3] = (bf16)a[3];
    o[4] = (bf16)b[0]; o[5] = (bf16)b[1]; o[6] = (bf16)b[2]; o[7] = (bf16)b[3];
    *(bf16x8*)(img + (size_t)c * 8) = o;
}

// ============================================================
// Tall-skinny, whole-K-in-LDS, KERNEL-SCALE PIPELINED.
// Block = 64 rows x 1024 cols, grid 256 (x read exactly once).
// 8 waves; per phase each wave owns 64 rows x 64 cols (acc[4][4]).
//   Phase 1 (mu, cols 0-511): K-loop with CHUNKED staging — 4 chunks
//     of 8 tiles; gload(c+1) in flight during chunk-c compute;
//     vmcnt(8) per chunk (counted: leaves 2-deep B prefetch alive);
//     one barrier per chunk. Then store mu (33 MB, fire-and-forget).
//   Phase 2 (logvar): K-loop over the SAME resident LDS, zero
//     barriers, zero staging; mu stores drain underneath. Store lv.
//   B: global->VGPR 2-tile ping-pong from fragment image (L2-res).
// FIFO ledger/chunk c>0: outstanding at vmcnt(8) = gload(c):8 oldest
// + B(next2):8 youngest -> vmcnt(8) drains exactly gload(c). c=0:
// vmcnt(0) drains gload(0) (only thing in flight). lgkm(0)+barrier
// per chunk makes cvt-writes visible; reads of chunk c happen only
// after its barrier. B waits are compiler-counted off register deps.
// ============================================================
__global__ __launch_bounds__(512, 1) void gpe_tall3(
    const float* __restrict__ x,
    const bf16* __restrict__ wimg,
    const float* __restrict__ b_mu,
    const float* __restrict__ b_logvar,
    float* __restrict__ out)         // [2][16384][512]
{
    __shared__ __align__(16) bf16 Alds[64 * 1024];   // 128 KB

    const int tid  = threadIdx.x;
    const int lane = tid & 63;
    const int wc   = tid >> 6;        // 0..7 : 64-col band within phase half
    const int fr   = lane & 15;
    const int g16  = lane >> 4;       // 0..3
    const int frx  = fr & 7;          // read-swizzle XOR
    const int bm   = blockIdx.x;      // 0..255 : 64-row slice

    // ---- staging geometry (verified r13: writes 8/bank = floor) ----
    const int arow = tid >> 3;                        // 0..63
    const int sl0  = tid & 7;
    const int rx   = arow & 7;
    const float* __restrict__ Asrc = x + (size_t)(bm * 64 + arow) * K_TOT;

    f32x4 stg[8];
    auto gload = [&](int c) {
#pragma unroll
        for (int j = 0; j < 4; ++j) {
            const int s = c * 32 + sl0 + 8 * j;
            stg[2 * j]     = *(const f32x4*)(Asrc + s * 8);
            stg[2 * j + 1] = *(const f32x4*)(Asrc + s * 8 + 4);
        }
    };
    auto cvtwrite = [&](int c) {
#pragma unroll
        for (int j = 0; j < 4; ++j) {
            const int s = c * 32 + sl0 + 8 * j;
            bf16x8 w;
#pragma unroll
            for (int q = 0; q < 4; ++q) {
                w[q]     = (bf16)stg[2 * j][q];
                w[q + 4] = (bf16)stg[2 * j + 1][q];
            }
            *(bf16x8*)&Alds[arow * 1024 + (s ^ rx) * 8] = w;
        }
    };

    // ---- B: 4 estrips per wave per phase ----
    const bf16* __restrict__ bl = wimg + lane * 8;
    bf16x8 bvA[4], bvB[4];
    auto loadB = [&](size_t e0, int t, bf16x8 (&bv)[4]) {
#pragma unroll
        for (int ns = 0; ns < 4; ++ns)
            bv[ns] = *(const bf16x8*)(bl + e0 + (size_t)ns * 16384 + t * 512);
    };

    f32x4 acc[4][4];
#pragma unroll
    for (int m = 0; m < 4; ++m)
#pragma unroll
        for (int n = 0; n < 4; ++n)
            acc[m][n] = (f32x4){0.f, 0.f, 0.f, 0.f};

    const size_t e0p0 = (size_t)(wc * 4) * 16384;        // phase-1 estrip base
    const size_t e0p1 = (size_t)(32 + wc * 4) * 16384;   // phase-2

#define TILE_BODY(T, E0, BVC)                                                  \
    {                                                                          \
        const int t = (T);                                                     \
        bf16x8 afc[4];                                                         \
        _Pragma("unroll")                                                      \
        for (int m = 0; m < 4; ++m)                                            \
            afc[m] = *(const bf16x8*)&Alds[(m * 16 + fr) * 1024                \
                                           + ((t * 4 + g16) ^ frx) * 8];       \
        __builtin_amdgcn_s_setprio(1);                                         \
        _Pragma("unroll")                                                      \
        for (int ns = 0; ns < 4; ++ns)                                         \
            _Pragma("unroll")                                                  \
            for (int m = 0; m < 4; ++m)                                        \
                acc[m][ns] = __builtin_amdgcn_mfma_f32_16x16x32_bf16(          \
                    afc[m], BVC[ns], acc[m][ns], 0, 0, 0);                     \
        __builtin_amdgcn_s_setprio(0);                                         \
        if (t + 2 < NT) loadB(E0, t + 2, BVC);                                 \
    }

    // ================= phase 1: mu + chunked staging =================
    gload(0);
    for (int c = 0; c < 4; ++c) {
        if (c == 0) asm volatile("s_waitcnt vmcnt(0)" ::: "memory");
        else        asm volatile("s_waitcnt vmcnt(8)" ::: "memory");
        cvtwrite(c);
        if (c < 3) gload(c + 1);
        if (c == 0) { loadB(e0p0, 0, bvA); loadB(e0p0, 1, bvB); }
        asm volatile("s_waitcnt lgkmcnt(0)" ::: "memory");
        __builtin_amdgcn_s_barrier();
#pragma unroll
        for (int tt = 0; tt < 8; tt += 2) {
            TILE_BODY(c * 8 + tt,     e0p0, bvA)
            TILE_BODY(c * 8 + tt + 1, e0p0, bvB)
        }
    }

    // phase-2 B prologue first (loads), then mu stores (drain in background)
    loadB(e0p1, 0, bvA);
    loadB(e0p1, 1, bvB);
    {
        float* __restrict__ obase = out;              // mu half
#pragma unroll
        for (int m = 0; m < 4; ++m) {
            const int row0 = bm * 64 + m * 16 + g16 * 4;
#pragma unroll
            for (int ns = 0; ns < 4; ++ns) {
                const int cl = wc * 64 + ns * 16 + fr;
                const float bvs = b_mu[cl];
#pragma unroll
                for (int j = 0; j < 4; ++j)
                    obase[(size_t)(row0 + j) * D_EMB + cl] = acc[m][ns][j] + bvs;
            }
        }
    }

    // ================= phase 2: logvar, pure compute =================
#pragma unroll
    for (int m = 0; m < 4; ++m)
#pragma unroll
        for (int n = 0; n < 4; ++n)
            acc[m][n] = (f32x4){0.f, 0.f, 0.f, 0.f};

#pragma unroll
    for (int tt = 0; tt < NT; tt += 2) {
        TILE_BODY(tt,     e0p1, bvA)
        TILE_BODY(tt + 1, e0p1, bvB)
    }
#undef TILE_BODY

    {
        float* __restrict__ obase = out + (size_t)M_TOT * D_EMB;   // logvar half
#pragma unroll
        for (int m = 0; m < 4; ++m) {
            const int row0 = bm * 64 + m * 16 + g16 * 4;
#pragma unroll
            for (int ns = 0; ns < 4; ++ns) {
                const int cl = wc * 64 + ns * 16 + fr;
                const float bvs = b_logvar[cl];
#pragma unroll
                for (int j = 0; j < 4; ++j)
                    obase[(size_t)(row0 + j) * D_EMB + cl] =
                        __expf(0.5f * (acc[m][ns][j] + bvs));
            }
        }
    }
}

// ============================================================
// Fallback (no workspace): round-1 f32-staging GEMM
// ============================================================
#define LDS_STRIDE 40
__global__ __launch_bounds__(256) void gpe_gemm_fb(
    const float* __restrict__ x, const float* __restrict__ W_mu,
    const float* __restrict__ b_mu, const float* __restrict__ W_logvar,
    const float* __restrict__ b_logvar, float* __restrict__ out)
{
    __shared__ __align__(16) bf16 As[128][LDS_STRIDE];
    __shared__ __align__(16) bf16 Bs[128][LDS_STRIDE];
    const int tid = threadIdx.x, lane = tid & 63, wid = tid >> 6;
    const int wr = wid >> 1, wcn = wid & 1;
    const int bn = blockIdx.x & 7, bm = blockIdx.x >> 3;
    const int ebase = bn * 128;
    const bool is_mu = (ebase < D_EMB);
    const float* Wp = is_mu ? (W_mu + (size_t)ebase * K_TOT)
                            : (W_logvar + (size_t)(ebase - D_EMB) * K_TOT);
    const float* bias = is_mu ? b_mu : b_logvar;
    const int cbase = is_mu ? ebase : (ebase - D_EMB);
    float* obase = is_mu ? out : (out + (size_t)M_TOT * D_EMB);
    const float* Ap = x + (size_t)(bm * 128) * K_TOT;
    f32x4 acc[4][4];
#pragma unroll
    for (int m = 0; m < 4; ++m)
#pragma unroll
        for (int n = 0; n < 4; ++n) acc[m][n] = (f32x4){0.f, 0.f, 0.f, 0.f};
    const int fr = lane & 15, fk = (lane >> 4) * 8;
    const int arow = wr * 64 + fr, brow = wcn * 64 + fr;
    for (int kt = 0; kt < K_TOT / 32; ++kt) {
        const int k0 = kt * 32;
#pragma unroll
        for (int s = 0; s < 4; ++s) {
            const int idx = s * 256 + tid;
            const int row = idx >> 3, col = (idx & 7) << 2;
            f32x4 va = *reinterpret_cast<const f32x4*>(Ap + (size_t)row * K_TOT + k0 + col);
            f32x4 vb = *reinterpret_cast<const f32x4*>(Wp + (size_t)row * K_TOT + k0 + col);
            bf16x4 ha, hb;
#pragma unroll
            for (int j = 0; j < 4; ++j) { ha[j] = (bf16)va[j]; hb[j] = (bf16)vb[j]; }
            *reinterpret_cast<bf16x4*>(&As[row][col]) = ha;
            *reinterpret_cast<bf16x4*>(&Bs[row][col]) = hb;
        }
        __syncthreads();
        bf16x8 af[4], bfv[4];
#pragma unroll
        for (int m = 0; m < 4; ++m)
            af[m] = *reinterpret_cast<const bf16x8*>(&As[arow + m * 16][fk]);
#pragma unroll
        for (int n = 0; n < 4; ++n)
            bfv[n] = *reinterpret_cast<const bf16x8*>(&Bs[brow + n * 16][fk]);
#pragma unroll
        for (int m = 0; m < 4; ++m)
#pragma unroll
            for (int n = 0; n < 4; ++n)
                acc[m][n] = __builtin_amdgcn_mfma_f32_16x16x32_bf16(af[m], bfv[n], acc[m][n], 0, 0, 0);
        __syncthreads();
    }
#pragma unroll
    for (int m = 0; m < 4; ++m) {
        const int rbase = bm * 128 + wr * 64 + m * 16 + (lane >> 4) * 4;
#pragma unroll
        for (int n = 0; n < 4; ++n) {
            const int c = cbase + wcn * 64 + n * 16 + (lane & 15);
            const float bv = bias[c];
#pragma unroll
            for (int j = 0; j < 4; ++j) {
                float v = acc[m][n][j] + bv;
                if (!is_mu) v = __expf(0.5f * v);
                obase[(size_t)(rbase + j) * D_EMB + c] = v;
            }
        }
    }
}

extern "C" void kernel_launch(void* const* d_in, const int* in_sizes, int n_in,
                              void* d_out, int out_size, void* d_ws, size_t ws_size,
                              hipStream_t stream) {
    const float* x        = (const float*)d_in[0];
    const float* W_mu     = (const float*)d_in[1];
    const float* b_mu     = (const float*)d_in[2];
    const float* W_logvar = (const float*)d_in[3];
    const float* b_logvar = (const float*)d_in[4];
    float* out = (float*)d_out;

    const size_t ws_needed = (size_t)1024 * 1024 * sizeof(bf16);   // 2 MB W image

    if (ws_size >= ws_needed) {
        bf16* wimg = (bf16*)d_ws;
        cvt_w_img<<<512, 256, 0, stream>>>(W_mu, W_logvar, wimg);
        gpe_tall3<<<256, 512, 0, stream>>>(x, wimg, b_mu, b_logvar, out);
    } else {
        gpe_gemm_fb<<<1024, 256, 0, stream>>>(x, W_mu, b_mu, W_logvar, b_logvar, out);
    }
}